// Round 10
// baseline (208.446 us; speedup 1.0000x reference)
//
#include <hip/hip_runtime.h>

#define N_NODES 5000
#define N_EDGES 160000
#define BATCH 2
#define TSTEPS 12
#define ROWS (BATCH*N_NODES)   // 10000
#define RB 16                  // rows per block (k_p / k_lstm)
#define NRB (ROWS/RB)          // 625
#define BIGP 1e30f

typedef _Float16 half8_t __attribute__((ext_vector_type(8)));
typedef float f32x4 __attribute__((ext_vector_type(4)));

// ---------------- k1: degree count (0..624) + WFB fragments (625..688) + permuted bias (689) ----------------
// WFB[(kt4*16+ct)*512 + lane*8 + j]:
//   kt4 0,1 : M[f][colP] with M = W2 @ W_ih^T (f = kt4*32+(lane>>4)*8+j)   [fold of layer-2 W2]
//   kt4 2,3 : W_hh[colP][k] (k = (kt4-2)*32+(lane>>4)*8+j)
//   colP = (ct&3)*64 + (ct>>2)*16 + (lane&15)   (gate-interleave permutation)
__global__ void k1(const int* __restrict__ ei, int* __restrict__ cnt,
                   const float* __restrict__ W_ih, const float* __restrict__ W_hh,
                   const float* __restrict__ W2,
                   const float* __restrict__ b_ih, const float* __restrict__ b_hh,
                   const float* __restrict__ b2,
                   _Float16* __restrict__ WFB, float* __restrict__ biasP) {
  int bid = blockIdx.x;
  if (bid < 625) {
    int e = bid*256 + threadIdx.x;
    if (e < N_EDGES) atomicAdd(&cnt[ei[N_EDGES + e]], 1);
    return;
  }
  bid -= 625;
  if (bid < 64) {
    #pragma unroll
    for (int h=0; h<2; ++h){
      int e = bid*512 + h*256 + threadIdx.x;    // 0..32767
      int kt4 = e >> 13;
      int rem = e & 8191;
      int ct  = rem >> 9;
      int le  = rem & 511;
      int lane = le >> 3, j = le & 7;
      int colP = (ct&3)*64 + (ct>>2)*16 + (lane&15);
      int kk   = (kt4&1)*32 + (lane>>4)*8 + j;
      float v;
      if (kt4 < 2){
        float s = 0.f;
        #pragma unroll 8
        for (int m=0;m<64;m++) s = fmaf(W2[kk*64+m], W_ih[colP*64+m], s);
        v = s;
      } else {
        v = W_hh[colP*64 + kk];
      }
      WFB[e] = (_Float16)v;
    }
    return;
  }
  // bias block: biasP[j] = b_ih[o]+b_hh[o]+sum_k b2[k]*W_ih[o][k], o = unpermuted col
  int jj = threadIdx.x;
  int ct = jj >> 4, c16 = jj & 15;
  int o = (ct&3)*64 + (ct>>2)*16 + c16;
  float s = b_ih[o] + b_hh[o];
  for (int k=0;k<64;k++) s = fmaf(b2[k], W_ih[o*64+k], s);
  biasP[jj] = s;
}

__global__ void k_scan(const int* __restrict__ cnt, int* __restrict__ row_ptr,
                       float* __restrict__ dinv) {
  __shared__ int sums[1024];
  int tid = threadIdx.x;
  constexpr int C = (N_NODES + 1023)/1024; // 5
  int base = tid*C;
  int local[C];
  int s = 0;
  #pragma unroll
  for (int i=0;i<C;i++){ int idx=base+i; int v=(idx<N_NODES)?cnt[idx]:0; local[i]=s; s+=v; }
  sums[tid]=s; __syncthreads();
  for (int off=1; off<1024; off<<=1) {
    int v = sums[tid];
    int add = (tid>=off)? sums[tid-off]:0;
    __syncthreads();
    sums[tid] = v + add;
    __syncthreads();
  }
  int excl = (tid>0)? sums[tid-1]:0;
  #pragma unroll
  for (int i=0;i<C;i++){ int idx=base+i; if(idx<N_NODES) row_ptr[idx]=excl+local[i]; }
  if (tid==0) row_ptr[N_NODES] = sums[1023];
  #pragma unroll
  for (int i=0;i<C;i++){ int idx=base+i; if(idx<N_NODES) dinv[idx]=rsqrtf((float)(cnt[idx]+1)); }
}

// ---------------- k2: CSR fill (blocks 0..624) + xdT build (625..1249) ----------------
// xdT[n][c] = x[c*N + n] * dinv[n] for c<24 (c = b*12+t), 0 for pad c in 24..31
__global__ void k2(const int* __restrict__ ei, const int* __restrict__ row_ptr,
                   int* __restrict__ fill, int* __restrict__ csr_src,
                   const float* __restrict__ x, const float* __restrict__ dinv,
                   float* __restrict__ xdT) {
  int bid = blockIdx.x;
  if (bid < 625) {
    int e = bid*256 + threadIdx.x;
    if (e < N_EDGES) {
      int src = ei[e], dst = ei[N_EDGES+e];
      int pos = row_ptr[dst] + atomicAdd(&fill[dst],1);
      csr_src[pos] = src;
    }
    return;
  }
  int i = (bid-625)*256 + threadIdx.x;   // 0..159999 = 5000*32
  int n = i >> 5, c = i & 31;
  xdT[i] = (c < 24) ? x[c*N_NODES + n] * dinv[n] : 0.f;
}

// ---------------- k_p: P[n][tb] = dinv[n]*(sum_src xdT[src][tb] + xdT[n][tb]) ----------------
__global__ void __launch_bounds__(256) k_p(
    const float* __restrict__ xdT,
    const int* __restrict__ row_ptr, const int* __restrict__ csr_src,
    const float* __restrict__ dinv, float* __restrict__ P)
{
  int tid = threadIdx.x;
  int wv = tid >> 6, lane = tid & 63;
  int s8 = lane >> 3, g8 = lane & 7;
  #pragma unroll
  for (int i=0;i<4;i++){
    int n = blockIdx.x*RB + wv*4 + i;
    if (n >= N_NODES) continue;
    int e0 = row_ptr[n], e1 = row_ptr[n+1];
    float ax=0.f, ay=0.f, az=0.f, aw=0.f;
    int e = e0 + s8;
    for (; e + 8 < e1; e += 16){
      int i1 = csr_src[e], i2 = csr_src[e+8];
      float4 v1 = *(const float4*)&xdT[i1*32 + g8*4];
      float4 v2 = *(const float4*)&xdT[i2*32 + g8*4];
      ax += v1.x + v2.x; ay += v1.y + v2.y;
      az += v1.z + v2.z; aw += v1.w + v2.w;
    }
    if (e < e1){
      int i1 = csr_src[e];
      float4 v1 = *(const float4*)&xdT[i1*32 + g8*4];
      ax += v1.x; ay += v1.y; az += v1.z; aw += v1.w;
    }
    #pragma unroll
    for (int m=8; m<=32; m<<=1){
      ax += __shfl_xor(ax, m, 64); ay += __shfl_xor(ay, m, 64);
      az += __shfl_xor(az, m, 64); aw += __shfl_xor(aw, m, 64);
    }
    if (s8 == 0){
      float4 sv = *(const float4*)&xdT[n*32 + g8*4];
      float dn = dinv[n];
      float4 o;
      o.x = dn*(ax + sv.x); o.y = dn*(ay + sv.y);
      o.z = dn*(az + sv.z); o.w = dn*(aw + sv.w);
      *(float4*)&P[n*32 + g8*4] = o;
    }
  }
}

// ---------------- k_hinge: agg2[t][b*N+n][64] = dn*( sum_src w_s*relu(W1f*p_s+b1f) + dn*relu(W1f*p_n+b1f) )
// Rank-1 hinge closed form: sort neighbor p ascending, prefix sums of (w, w*p),
// per feature f: active set split at theta_f = -b1f/W1f found by binary search.
__global__ void __launch_bounds__(256) k_hinge(
    const float* __restrict__ P,        // [n][32], c = b*12+t in 0..23
    const int* __restrict__ row_ptr, const int* __restrict__ csr_src,
    const float* __restrict__ dinv,
    const float* __restrict__ W1, const float* __restrict__ b1,
    _Float16* __restrict__ agg2)        // [t][b*N+n][64] f16
{
  __shared__ float nP[4][64][28];   // neighbor P rows (stride 28 floats = 112B, 16B-aligned rows)
  __shared__ float nW[4][64];       // neighbor dinv
  __shared__ float sp[4][64];       // sorted p
  __shared__ float sW[4][64];       // prefix sum of w
  __shared__ float sWP[4][64];      // prefix sum of w*p
  int tid = threadIdx.x;
  int wv = tid >> 6, lane = tid & 63;
  int n = blockIdx.x*4 + wv;        // grid 1250 * 4 waves = 5000 exact
  float w1f = W1[lane], b1f = b1[lane];
  float dn = dinv[n];
  int e0 = row_ptr[n], e1 = row_ptr[n+1];
  int deg = e1 - e0;

  if (deg <= 64 && lane < deg){
    int s = csr_src[e0 + lane];
    nW[wv][lane] = dinv[s];
    const float* pr = &P[s*32];
    #pragma unroll
    for (int q=0;q<6;q++){
      float4 v = *(const float4*)(pr + q*4);
      *(float4*)&nP[wv][lane][q*4] = v;
    }
  }
  __syncthreads();

  if (deg > 64){
    // exact fallback (statistically never for this graph): direct per-edge evaluation
    for (int c=0;c<24;++c){
      float S = 0.f;
      for (int e=e0; e<e1; ++e){
        int s = csr_src[e];
        float ps = P[s*32 + c];
        S += dinv[s]*fmaxf(fmaf(w1f, ps, b1f), 0.f);
      }
      float pself = P[n*32 + c];
      S += dn*fmaxf(fmaf(w1f, pself, b1f), 0.f);
      int b = c/12, t = c - b*12;
      agg2[((size_t)t*ROWS + b*N_NODES + n)*64 + lane] = (_Float16)(dn*S);
    }
    return;
  }

  for (int c=0; c<24; ++c){
    float p = (lane < deg) ? nP[wv][lane][c] : BIGP;  // finite pad: 0*BIGP = 0, no NaN
    float w = (lane < deg) ? nW[wv][lane] : 0.f;
    int idx = lane;
    // bitonic sort ascending over 64 lanes, (p, w) with index tie-break
    #pragma unroll
    for (int k=2; k<=64; k<<=1){
      #pragma unroll
      for (int j=k>>1; j>0; j>>=1){
        float p2 = __shfl_xor(p, j, 64);
        float w2 = __shfl_xor(w, j, 64);
        int   i2 = __shfl_xor(idx, j, 64);
        bool takeMin = (((lane & j) == 0) == ((lane & k) == 0));
        bool less = (p2 < p) || ((p2 == p) && (i2 < idx));
        bool pick = (less == takeMin);
        p = pick ? p2 : p;
        w = pick ? w2 : w;
        idx = pick ? i2 : idx;
      }
    }
    // inclusive prefix scans over sorted lanes
    float Wn = w, WPn = w*p;
    #pragma unroll
    for (int d=1; d<64; d<<=1){
      float tW = __shfl_up(Wn, d, 64);
      float tP = __shfl_up(WPn, d, 64);
      if (lane >= d){ Wn += tW; WPn += tP; }
    }
    sp[wv][lane] = p; sW[wv][lane] = Wn; sWP[wv][lane] = WPn;
    float Wtot  = __shfl(Wn, 63, 64);
    float WPtot = __shfl(WPn, 63, 64);
    // feature evaluation: lane = f
    float S;
    if (w1f != 0.f){
      float theta = -b1f / w1f;
      int kk = 0;
      #pragma unroll
      for (int st=64; st>0; st>>=1){
        int t2 = kk + st;
        if (t2 <= 64 && sp[wv][t2-1] < theta) kk = t2;
      }
      float Wb  = (kk>0)? sW[wv][kk-1]  : 0.f;
      float WPb = (kk>0)? sWP[wv][kk-1] : 0.f;
      if (w1f > 0.f) S = w1f*(WPtot - WPb) + b1f*(Wtot - Wb);
      else           S = w1f*WPb + b1f*Wb;
    } else {
      S = fmaxf(b1f, 0.f) * Wtot;
    }
    float pself = P[n*32 + c];
    S += dn * fmaxf(fmaf(w1f, pself, b1f), 0.f);
    int b = c/12, t = c - b*12;
    agg2[((size_t)t*ROWS + b*N_NODES + n)*64 + lane] = (_Float16)(dn * S);
  }
}

// ---------------- k_lstm: persistent 12-step LSTM, f16 MFMA, weights in VGPRs, in-register gates ----------------
__global__ void __launch_bounds__(256) k_lstm(
    const _Float16* __restrict__ agg2,   // [t][r][64] f16
    const _Float16* __restrict__ WF,     // 4 kt4-tiles x 16 ct, permuted cols, f16
    const float* __restrict__ biasP,
    const float* __restrict__ fc_w, const float* __restrict__ fc_b,
    float* __restrict__ out)
{
  __shared__ _Float16 sH[2][RB][72];   // h, f16, double-buffered
  __shared__ float sRed[4][16];
  int tid = threadIdx.x;
  int r0 = blockIdx.x*RB;
  int wv = tid >> 6, lane = tid & 63;
  int row = lane & 15, kg = lane >> 4;
  int j = wv*16 + row;                 // this thread's h-column (gate-permuted layout)

  // weights: all 16 (kt4, ct=wv*4+i) tiles into registers, once
  half8_t Wr[4][4];
  #pragma unroll
  for (int kt4=0; kt4<4; ++kt4)
    #pragma unroll
    for (int i=0;i<4;i++)
      Wr[kt4][i] = *(const half8_t*)(WF + ((size_t)(kt4*16 + wv*4 + i))*512 + (size_t)lane*8);

  float bias[4];
  #pragma unroll
  for (int i=0;i<4;i++) bias[i] = biasP[(wv*4+i)*16 + row];

  float creg[4] = {0.f,0.f,0.f,0.f};
  float hn[4]   = {0.f,0.f,0.f,0.f};

  // prefetch agg A-tile for t=0 (already f16 fragments)
  half8_t pa0, pa1;
  {
    const _Float16* base = &agg2[((size_t)(r0 + row))*64 + kg*8];
    pa0 = *(const half8_t*)base;
    pa1 = *(const half8_t*)(base + 32);
  }

  int pb = 0;
  for (int t=0; t<TSTEPS; ++t){
    half8_t Af0 = pa0, Af1 = pa1;
    if (t+1 < TSTEPS){
      const _Float16* base = &agg2[((size_t)(t+1)*ROWS + r0 + row)*64 + kg*8];
      pa0 = *(const half8_t*)base;
      pa1 = *(const half8_t*)(base + 32);
    }
    // H-fragments (K 64..127) from LDS
    half8_t Hf0, Hf1;
    if (t > 0){
      Hf0 = *(const half8_t*)&sH[pb][row][kg*8];
      Hf1 = *(const half8_t*)&sH[pb][row][32 + kg*8];
    }
    f32x4 acc[4];
    #pragma unroll
    for (int i=0;i<4;i++){ acc[i][0]=bias[i]; acc[i][1]=bias[i]; acc[i][2]=bias[i]; acc[i][3]=bias[i]; }
    #pragma unroll
    for (int i=0;i<4;i++){
      f32x4 a = acc[i];
      a = __builtin_amdgcn_mfma_f32_16x16x32_f16(Af0, Wr[0][i], a, 0, 0, 0);
      a = __builtin_amdgcn_mfma_f32_16x16x32_f16(Af1, Wr[1][i], a, 0, 0, 0);
      if (t > 0){
        a = __builtin_amdgcn_mfma_f32_16x16x32_f16(Hf0, Wr[2][i], a, 0, 0, 0);
        a = __builtin_amdgcn_mfma_f32_16x16x32_f16(Hf1, Wr[3][i], a, 0, 0, 0);
      }
      acc[i] = a;
    }
    // in-register LSTM update: acc[i][rr] = gate_i for row kg*4+rr, col j
    #pragma unroll
    for (int rr=0;rr<4;rr++){
      float gi = acc[0][rr], gf = acc[1][rr], gg = acc[2][rr], go = acc[3][rr];
      float si = 1.f/(1.f + __expf(-gi));
      float sf = 1.f/(1.f + __expf(-gf));
      float so = 1.f/(1.f + __expf(-go));
      float tg = 2.f/(1.f + __expf(-2.f*gg)) - 1.f;
      float cn = sf*creg[rr] + si*tg;
      creg[rr] = cn;
      float tc = 2.f/(1.f + __expf(-2.f*cn)) - 1.f;
      hn[rr] = so*tc;
      sH[pb^1][kg*4+rr][j] = (_Float16)hn[rr];
    }
    __syncthreads();
    pb ^= 1;
  }
  // final projection: out[r] = sum_j h[r][j]*fc_w[j] + fc_b
  float fw = fc_w[j];
  #pragma unroll
  for (int rr=0;rr<4;rr++){
    float pv = hn[rr]*fw;
    pv += __shfl_xor(pv, 1, 64);
    pv += __shfl_xor(pv, 2, 64);
    pv += __shfl_xor(pv, 4, 64);
    pv += __shfl_xor(pv, 8, 64);
    if (row == 0) sRed[wv][kg*4+rr] = pv;
  }
  __syncthreads();
  if (tid < 16)
    out[r0 + tid] = sRed[0][tid] + sRed[1][tid] + sRed[2][tid] + sRed[3][tid] + fc_b[0];
}

extern "C" void kernel_launch(void* const* d_in, const int* in_sizes, int n_in,
                              void* d_out, int out_size, void* d_ws, size_t ws_size,
                              hipStream_t stream) {
  const float* x    = (const float*)d_in[0];
  const int*   ei   = (const int*)d_in[1];
  const float* W1   = (const float*)d_in[2];
  const float* b1   = (const float*)d_in[3];
  const float* W2   = (const float*)d_in[4];
  const float* b2   = (const float*)d_in[5];
  const float* W_ih = (const float*)d_in[6];
  const float* W_hh = (const float*)d_in[7];
  const float* b_ih = (const float*)d_in[8];
  const float* b_hh = (const float*)d_in[9];
  const float* fc_w = (const float*)d_in[10];
  const float* fc_b = (const float*)d_in[11];
  float* out = (float*)d_out;

  char* ws = (char*)d_ws;
  size_t off = 0;
  auto alloc = [&](size_t bytes)->void* { void* p = ws + off; off += (bytes + 255) & ~255ul; return p; };
  float*     dinv    = (float*)alloc(N_NODES*4);
  int*       cntfill = (int*)alloc(2*N_NODES*4);      // [0:N)=cnt, [N:2N)=fill
  int*       row_ptr = (int*)alloc((N_NODES+1)*4);
  int*       csr_src = (int*)alloc(N_EDGES*4);
  _Float16*  WFB     = (_Float16*)alloc(4*16*512*2);  // 64 KB fragments (M fold + W_hh)
  float*     biasP   = (float*)alloc(256*4);
  float*     xdT     = (float*)alloc((size_t)N_NODES*32*4);        // 640 KB
  float*     P       = (float*)alloc((size_t)N_NODES*32*4);        // 640 KB
  _Float16*  agg2    = (_Float16*)alloc((size_t)TSTEPS*ROWS*64*2); // 15.4 MB

  int* cnt  = cntfill;
  int* fill = cntfill + N_NODES;

  hipMemsetAsync(cntfill, 0, 2*N_NODES*4, stream);

  k1     <<<690, 256, 0, stream>>>(ei, cnt, W_ih, W_hh, W2, b_ih, b_hh, b2, WFB, biasP);
  k_scan <<<1, 1024, 0, stream>>>(cnt, row_ptr, dinv);
  k2     <<<1250, 256, 0, stream>>>(ei, row_ptr, fill, csr_src, x, dinv, xdT);
  k_p    <<<(N_NODES+RB-1)/RB, 256, 0, stream>>>(xdT, row_ptr, csr_src, dinv, P);
  k_hinge<<<N_NODES/4, 256, 0, stream>>>(P, row_ptr, csr_src, dinv, W1, b1, agg2);
  k_lstm <<<NRB, 256, 0, stream>>>(agg2, WFB, biasP, fc_w, fc_b, out);
}

// Round 11
// 116.310 us; speedup vs baseline: 1.7922x; 1.7922x over previous
//
#include <hip/hip_runtime.h>

#define N_NODES 5000
#define N_EDGES 160000
#define BATCH 2
#define TSTEPS 12
#define ROWS (BATCH*N_NODES)   // 10000
#define RB 16                  // rows per block (k_pg / k_lstm)
#define NRB (ROWS/RB)          // 625

typedef _Float16 half8_t __attribute__((ext_vector_type(8)));
typedef float f32x4 __attribute__((ext_vector_type(4)));

// Bijective XCD swizzle for grid 7500 = 4*938 + 4*937 (gid = i*8 + xcd)
__device__ inline int swz7500(int gid){
  int xcd = gid & 7, i = gid >> 3;
  return (xcd < 4 ? xcd*938 : 3752 + (xcd-4)*937) + i;
}

// ---------------- k1: degree count (0..624) + WFB fragments (625..688) + permuted bias (689) ----------------
// WFB[(kt4*16+ct)*512 + lane*8 + j]:
//   kt4 0,1 : M[f][colP] with M = W2 @ W_ih^T (f = kt4*32+(lane>>4)*8+j)   [fold of layer-2 W2]
//   kt4 2,3 : W_hh[colP][k] (k = (kt4-2)*32+(lane>>4)*8+j)
//   colP = (ct&3)*64 + (ct>>2)*16 + (lane&15)   (gate-interleave permutation)
__global__ void k1(const int* __restrict__ ei, int* __restrict__ cnt,
                   const float* __restrict__ W_ih, const float* __restrict__ W_hh,
                   const float* __restrict__ W2,
                   const float* __restrict__ b_ih, const float* __restrict__ b_hh,
                   const float* __restrict__ b2,
                   _Float16* __restrict__ WFB, float* __restrict__ biasP) {
  int bid = blockIdx.x;
  if (bid < 625) {
    int e = bid*256 + threadIdx.x;
    if (e < N_EDGES) atomicAdd(&cnt[ei[N_EDGES + e]], 1);
    return;
  }
  bid -= 625;
  if (bid < 64) {
    #pragma unroll
    for (int h=0; h<2; ++h){
      int e = bid*512 + h*256 + threadIdx.x;    // 0..32767
      int kt4 = e >> 13;
      int rem = e & 8191;
      int ct  = rem >> 9;
      int le  = rem & 511;
      int lane = le >> 3, j = le & 7;
      int colP = (ct&3)*64 + (ct>>2)*16 + (lane&15);
      int kk   = (kt4&1)*32 + (lane>>4)*8 + j;
      float v;
      if (kt4 < 2){
        float s = 0.f;
        #pragma unroll 8
        for (int m=0;m<64;m++) s = fmaf(W2[kk*64+m], W_ih[colP*64+m], s);
        v = s;
      } else {
        v = W_hh[colP*64 + kk];
      }
      WFB[e] = (_Float16)v;
    }
    return;
  }
  // bias block: biasP[j] = b_ih[o]+b_hh[o]+sum_k b2[k]*W_ih[o][k], o = unpermuted col
  int jj = threadIdx.x;
  int ct = jj >> 4, c16 = jj & 15;
  int o = (ct&3)*64 + (ct>>2)*16 + c16;
  float s = b_ih[o] + b_hh[o];
  for (int k=0;k<64;k++) s = fmaf(b2[k], W_ih[o*64+k], s);
  biasP[jj] = s;
}

__global__ void k_scan(const int* __restrict__ cnt, int* __restrict__ row_ptr,
                       float* __restrict__ dinv) {
  __shared__ int sums[1024];
  int tid = threadIdx.x;
  constexpr int C = (N_NODES + 1023)/1024; // 5
  int base = tid*C;
  int local[C];
  int s = 0;
  #pragma unroll
  for (int i=0;i<C;i++){ int idx=base+i; int v=(idx<N_NODES)?cnt[idx]:0; local[i]=s; s+=v; }
  sums[tid]=s; __syncthreads();
  for (int off=1; off<1024; off<<=1) {
    int v = sums[tid];
    int add = (tid>=off)? sums[tid-off]:0;
    __syncthreads();
    sums[tid] = v + add;
    __syncthreads();
  }
  int excl = (tid>0)? sums[tid-1]:0;
  #pragma unroll
  for (int i=0;i<C;i++){ int idx=base+i; if(idx<N_NODES) row_ptr[idx]=excl+local[i]; }
  if (tid==0) row_ptr[N_NODES] = sums[1023];
  #pragma unroll
  for (int i=0;i<C;i++){ int idx=base+i; if(idx<N_NODES) dinv[idx]=rsqrtf((float)(cnt[idx]+1)); }
}

// ---------------- k2: CSR fill (blocks 0..624) + xdT build (625..1249) ----------------
// xdT[n][c] = x[c*N + n] * dinv[n] for c<24 (c = b*12+t), 0 for pad c in 24..31
__global__ void k2(const int* __restrict__ ei, const int* __restrict__ row_ptr,
                   int* __restrict__ fill, int* __restrict__ csr_src,
                   const float* __restrict__ x, const float* __restrict__ dinv,
                   float* __restrict__ xdT) {
  int bid = blockIdx.x;
  if (bid < 625) {
    int e = bid*256 + threadIdx.x;
    if (e < N_EDGES) {
      int src = ei[e], dst = ei[N_EDGES+e];
      int pos = row_ptr[dst] + atomicAdd(&fill[dst],1);
      csr_src[pos] = src;
    }
    return;
  }
  int i = (bid-625)*256 + threadIdx.x;   // 0..159999 = 5000*32
  int n = i >> 5, c = i & 31;
  xdT[i] = (c < 24) ? x[c*N_NODES + n] * dinv[n] : 0.f;
}

// ---------------- k_pg: P (layer-1 SpMV, all 24 c) + g2 production, fused ----------------
// g2[t][n][col], col = b*64 + f  (256B per (t,n) covering both batches)
// g2 = f16( dinv[n] * relu(P[n][c]*W1[f]+b1[f]) ), c = b*12+t
__global__ void __launch_bounds__(256) k_pg(
    const float* __restrict__ xdT,
    const int* __restrict__ row_ptr, const int* __restrict__ csr_src,
    const float* __restrict__ dinv,
    const float* __restrict__ W1, const float* __restrict__ b1,
    _Float16* __restrict__ g2)
{
  __shared__ float sP[RB][26];    // [node][c], c<24
  __shared__ float sW1[64], sb1[64];
  int tid = threadIdx.x;
  if (tid < 64) { sW1[tid] = W1[tid]; sb1[tid] = b1[tid]; }
  int wv = tid >> 6, lane = tid & 63;
  int s8 = lane >> 3, g8 = lane & 7;
  int n0 = blockIdx.x*RB;
  #pragma unroll
  for (int i=0;i<4;i++){
    int lr = wv*4 + i;
    int n = n0 + lr;
    if (n >= N_NODES) continue;
    int e0 = row_ptr[n], e1 = row_ptr[n+1];
    float ax=0.f, ay=0.f, az=0.f, aw=0.f;
    int e = e0 + s8;
    for (; e + 8 < e1; e += 16){
      int i1 = csr_src[e], i2 = csr_src[e+8];
      float4 v1 = *(const float4*)&xdT[i1*32 + g8*4];
      float4 v2 = *(const float4*)&xdT[i2*32 + g8*4];
      ax += v1.x + v2.x; ay += v1.y + v2.y;
      az += v1.z + v2.z; aw += v1.w + v2.w;
    }
    if (e < e1){
      int i1 = csr_src[e];
      float4 v1 = *(const float4*)&xdT[i1*32 + g8*4];
      ax += v1.x; ay += v1.y; az += v1.z; aw += v1.w;
    }
    #pragma unroll
    for (int m=8; m<=32; m<<=1){
      ax += __shfl_xor(ax, m, 64); ay += __shfl_xor(ay, m, 64);
      az += __shfl_xor(az, m, 64); aw += __shfl_xor(aw, m, 64);
    }
    if (s8 == 0 && g8 < 6){
      float4 sv = *(const float4*)&xdT[n*32 + g8*4];
      float dn = dinv[n];
      sP[lr][g8*4+0] = dn*(ax + sv.x);
      sP[lr][g8*4+1] = dn*(ay + sv.y);
      sP[lr][g8*4+2] = dn*(az + sv.z);
      sP[lr][g8*4+3] = dn*(aw + sv.w);
    }
  }
  __syncthreads();
  // epilogue: 16 nodes x 12 t x 16 col-octets = 3072 half8 writes
  for (int u = tid; u < RB*12*16; u += 256){
    int node = u / 192;
    int rem  = u - node*192;
    int t  = rem >> 4;
    int oc = rem & 15;
    int b  = oc >> 3, f8 = oc & 7;
    int n = n0 + node;
    if (n >= N_NODES) continue;
    float p  = sP[node][b*12 + t];
    float dn = dinv[n];
    half8_t o;
    #pragma unroll
    for (int j=0;j<8;j++)
      o[j] = (_Float16)(dn * fmaxf(fmaf(p, sW1[f8*8+j], sb1[f8*8+j]), 0.f));
    *(half8_t*)&g2[((size_t)t*N_NODES + n)*128 + oc*8] = o;
  }
}

// ---------------- k_agg: agg2[t][r][64] (f16) = D^-1/2 (A+I) g2 ----------------
// One wave per node; 16 lanes cover both batches (256B per edge-t request);
// 2 timesteps per block (L2 slab 2.56MB < 4MB/XCD), edge loop 4-deep (8 loads in flight).
__global__ void __launch_bounds__(256) k_agg(
    const _Float16* __restrict__ g2,     // [t][n][128] f16
    const int* __restrict__ row_ptr, const int* __restrict__ csr_src,
    const float* __restrict__ dinv, _Float16* __restrict__ agg2)
{
  int tid = threadIdx.x;
  int wk = swz7500(blockIdx.x);
  int tg = wk / 1250;            // 0..5 -> timesteps 2tg, 2tg+1
  int nb = wk % 1250;
  int wv = tid >> 6, lane = tid & 63;
  int n = nb*4 + wv;             // one node per wave, always < 5000
  int slot = lane >> 4;          // 4 edge slots
  int l16 = lane & 15;           // col octet: b = l16>>3, f8 = l16&7
  int b = l16 >> 3, f8 = l16 & 7;
  const _Float16* gA = g2 + (size_t)(2*tg)*N_NODES*128;
  const size_t slab = (size_t)N_NODES*128;
  int e0 = row_ptr[n], e1 = row_ptr[n+1];
  float a0[8]={0,0,0,0,0,0,0,0}, a1[8]={0,0,0,0,0,0,0,0};
  int e = e0 + slot;
  for (; e + 12 < e1; e += 16){
    size_t oA = (size_t)csr_src[e]*128 + l16*8;
    size_t oB = (size_t)csr_src[e+4]*128 + l16*8;
    size_t oC = (size_t)csr_src[e+8]*128 + l16*8;
    size_t oD = (size_t)csr_src[e+12]*128 + l16*8;
    half8_t uA0 = *(const half8_t*)(gA + oA);
    half8_t uB0 = *(const half8_t*)(gA + oB);
    half8_t uC0 = *(const half8_t*)(gA + oC);
    half8_t uD0 = *(const half8_t*)(gA + oD);
    half8_t uA1 = *(const half8_t*)(gA + slab + oA);
    half8_t uB1 = *(const half8_t*)(gA + slab + oB);
    half8_t uC1 = *(const half8_t*)(gA + slab + oC);
    half8_t uD1 = *(const half8_t*)(gA + slab + oD);
    half8_t s0 = (uA0 + uB0) + (uC0 + uD0);   // v_pk_add_f16 (g ~0.01-scale)
    half8_t s1 = (uA1 + uB1) + (uC1 + uD1);
    #pragma unroll
    for (int j=0;j<8;j++){
      a0[j] += (float)s0[j]; a1[j] += (float)s1[j];
    }
  }
  for (; e < e1; e += 4){
    size_t oA = (size_t)csr_src[e]*128 + l16*8;
    half8_t uA0 = *(const half8_t*)(gA + oA);
    half8_t uA1 = *(const half8_t*)(gA + slab + oA);
    #pragma unroll
    for (int j=0;j<8;j++){
      a0[j] += (float)uA0[j]; a1[j] += (float)uA1[j];
    }
  }
  #pragma unroll
  for (int m=16; m<=32; m<<=1){
    #pragma unroll
    for (int j=0;j<8;j++){
      a0[j] += __shfl_xor(a0[j], m, 64);
      a1[j] += __shfl_xor(a1[j], m, 64);
    }
  }
  if (slot == 0){
    size_t so = (size_t)n*128 + l16*8;
    half8_t sv0 = *(const half8_t*)(gA + so);
    half8_t sv1 = *(const half8_t*)(gA + slab + so);
    float dn = dinv[n];
    half8_t q0, q1;
    #pragma unroll
    for (int j=0;j<8;j++){
      q0[j] = (_Float16)(dn*(a0[j] + (float)sv0[j]));
      q1[j] = (_Float16)(dn*(a1[j] + (float)sv1[j]));
    }
    size_t r64 = ((size_t)(2*tg)*ROWS + b*N_NODES + n)*64 + f8*8;
    *(half8_t*)&agg2[r64] = q0;
    *(half8_t*)&agg2[r64 + (size_t)ROWS*64] = q1;
  }
}

// ---------------- k_lstm: persistent 12-step LSTM, f16 MFMA, weights in VGPRs, in-register gates ----------------
__global__ void __launch_bounds__(256) k_lstm(
    const _Float16* __restrict__ agg2,   // [t][r][64] f16
    const _Float16* __restrict__ WF,     // 4 kt4-tiles x 16 ct, permuted cols, f16
    const float* __restrict__ biasP,
    const float* __restrict__ fc_w, const float* __restrict__ fc_b,
    float* __restrict__ out)
{
  __shared__ _Float16 sH[2][RB][72];   // h, f16, double-buffered
  __shared__ float sRed[4][16];
  int tid = threadIdx.x;
  int r0 = blockIdx.x*RB;
  int wv = tid >> 6, lane = tid & 63;
  int row = lane & 15, kg = lane >> 4;
  int j = wv*16 + row;                 // this thread's h-column (gate-permuted layout)

  // weights: all 16 (kt4, ct=wv*4+i) tiles into registers, once
  half8_t Wr[4][4];
  #pragma unroll
  for (int kt4=0; kt4<4; ++kt4)
    #pragma unroll
    for (int i=0;i<4;i++)
      Wr[kt4][i] = *(const half8_t*)(WF + ((size_t)(kt4*16 + wv*4 + i))*512 + (size_t)lane*8);

  float bias[4];
  #pragma unroll
  for (int i=0;i<4;i++) bias[i] = biasP[(wv*4+i)*16 + row];

  float creg[4] = {0.f,0.f,0.f,0.f};
  float hn[4]   = {0.f,0.f,0.f,0.f};

  // prefetch agg A-tile for t=0 (already f16 fragments)
  half8_t pa0, pa1;
  {
    const _Float16* base = &agg2[((size_t)(r0 + row))*64 + kg*8];
    pa0 = *(const half8_t*)base;
    pa1 = *(const half8_t*)(base + 32);
  }

  int pb = 0;
  for (int t=0; t<TSTEPS; ++t){
    half8_t Af0 = pa0, Af1 = pa1;
    if (t+1 < TSTEPS){
      const _Float16* base = &agg2[((size_t)(t+1)*ROWS + r0 + row)*64 + kg*8];
      pa0 = *(const half8_t*)base;
      pa1 = *(const half8_t*)(base + 32);
    }
    // H-fragments (K 64..127) from LDS
    half8_t Hf0, Hf1;
    if (t > 0){
      Hf0 = *(const half8_t*)&sH[pb][row][kg*8];
      Hf1 = *(const half8_t*)&sH[pb][row][32 + kg*8];
    }
    f32x4 acc[4];
    #pragma unroll
    for (int i=0;i<4;i++){ acc[i][0]=bias[i]; acc[i][1]=bias[i]; acc[i][2]=bias[i]; acc[i][3]=bias[i]; }
    #pragma unroll
    for (int i=0;i<4;i++){
      f32x4 a = acc[i];
      a = __builtin_amdgcn_mfma_f32_16x16x32_f16(Af0, Wr[0][i], a, 0, 0, 0);
      a = __builtin_amdgcn_mfma_f32_16x16x32_f16(Af1, Wr[1][i], a, 0, 0, 0);
      if (t > 0){
        a = __builtin_amdgcn_mfma_f32_16x16x32_f16(Hf0, Wr[2][i], a, 0, 0, 0);
        a = __builtin_amdgcn_mfma_f32_16x16x32_f16(Hf1, Wr[3][i], a, 0, 0, 0);
      }
      acc[i] = a;
    }
    // in-register LSTM update: acc[i][rr] = gate_i for row kg*4+rr, col j
    #pragma unroll
    for (int rr=0;rr<4;rr++){
      float gi = acc[0][rr], gf = acc[1][rr], gg = acc[2][rr], go = acc[3][rr];
      float si = 1.f/(1.f + __expf(-gi));
      float sf = 1.f/(1.f + __expf(-gf));
      float so = 1.f/(1.f + __expf(-go));
      float tg = 2.f/(1.f + __expf(-2.f*gg)) - 1.f;
      float cn = sf*creg[rr] + si*tg;
      creg[rr] = cn;
      float tc = 2.f/(1.f + __expf(-2.f*cn)) - 1.f;
      hn[rr] = so*tc;
      sH[pb^1][kg*4+rr][j] = (_Float16)hn[rr];
    }
    __syncthreads();
    pb ^= 1;
  }
  // final projection: out[r] = sum_j h[r][j]*fc_w[j] + fc_b
  float fw = fc_w[j];
  #pragma unroll
  for (int rr=0;rr<4;rr++){
    float pv = hn[rr]*fw;
    pv += __shfl_xor(pv, 1, 64);
    pv += __shfl_xor(pv, 2, 64);
    pv += __shfl_xor(pv, 4, 64);
    pv += __shfl_xor(pv, 8, 64);
    if (row == 0) sRed[wv][kg*4+rr] = pv;
  }
  __syncthreads();
  if (tid < 16)
    out[r0 + tid] = sRed[0][tid] + sRed[1][tid] + sRed[2][tid] + sRed[3][tid] + fc_b[0];
}

extern "C" void kernel_launch(void* const* d_in, const int* in_sizes, int n_in,
                              void* d_out, int out_size, void* d_ws, size_t ws_size,
                              hipStream_t stream) {
  const float* x    = (const float*)d_in[0];
  const int*   ei   = (const int*)d_in[1];
  const float* W1   = (const float*)d_in[2];
  const float* b1   = (const float*)d_in[3];
  const float* W2   = (const float*)d_in[4];
  const float* b2   = (const float*)d_in[5];
  const float* W_ih = (const float*)d_in[6];
  const float* W_hh = (const float*)d_in[7];
  const float* b_ih = (const float*)d_in[8];
  const float* b_hh = (const float*)d_in[9];
  const float* fc_w = (const float*)d_in[10];
  const float* fc_b = (const float*)d_in[11];
  float* out = (float*)d_out;

  char* ws = (char*)d_ws;
  size_t off = 0;
  auto alloc = [&](size_t bytes)->void* { void* p = ws + off; off += (bytes + 255) & ~255ul; return p; };
  float*     dinv    = (float*)alloc(N_NODES*4);
  int*       cntfill = (int*)alloc(2*N_NODES*4);      // [0:N)=cnt, [N:2N)=fill
  int*       row_ptr = (int*)alloc((N_NODES+1)*4);
  int*       csr_src = (int*)alloc(N_EDGES*4);
  _Float16*  WFB     = (_Float16*)alloc(4*16*512*2);  // 64 KB fragments (M fold + W_hh)
  float*     biasP   = (float*)alloc(256*4);
  float*     xdT     = (float*)alloc((size_t)N_NODES*32*4);    // 640 KB
  _Float16*  g2      = (_Float16*)alloc((size_t)TSTEPS*N_NODES*128*2); // 15.4 MB, [t][n][b*64+f]
  _Float16*  agg2    = (_Float16*)alloc((size_t)TSTEPS*ROWS*64*2);     // 15.4 MB

  int* cnt  = cntfill;
  int* fill = cntfill + N_NODES;

  hipMemsetAsync(cntfill, 0, 2*N_NODES*4, stream);

  k1    <<<690, 256, 0, stream>>>(ei, cnt, W_ih, W_hh, W2, b_ih, b_hh, b2, WFB, biasP);
  k_scan<<<1, 1024, 0, stream>>>(cnt, row_ptr, dinv);
  k2    <<<1250, 256, 0, stream>>>(ei, row_ptr, fill, csr_src, x, dinv, xdT);
  k_pg  <<<(N_NODES+RB-1)/RB, 256, 0, stream>>>(xdT, row_ptr, csr_src, dinv, W1, b1, g2);
  k_agg <<<7500, 256, 0, stream>>>(g2, row_ptr, csr_src, dinv, agg2);
  k_lstm<<<NRB, 256, 0, stream>>>(agg2, WFB, biasP, fc_w, fc_b, out);
}